// Round 3
// baseline (454.422 us; speedup 1.0000x reference)
//
#include <hip/hip_runtime.h>
#include <hip/hip_bf16.h>

typedef unsigned short u16;
typedef __attribute__((ext_vector_type(8))) short short8;
typedef __attribute__((ext_vector_type(4))) short short4v;
typedef __attribute__((ext_vector_type(8))) u16 u16x8;
typedef __attribute__((ext_vector_type(4))) u16 u16x4;
typedef __attribute__((ext_vector_type(4))) float f32x4;

__device__ __forceinline__ u16 f2bf(float f) {
  __hip_bfloat16 h = __float2bfloat16(f);
  u16 u;
  __builtin_memcpy(&u, &h, 2);
  return u;
}

__device__ __forceinline__ f32x4 mfma16(short8 a, short8 b, f32x4 c) {
  return __builtin_amdgcn_mfma_f32_16x16x32_bf16(a, b, c, 0, 0, 0);
}

__device__ __forceinline__ f32x4 mfma16x16(short4v a, short4v b, f32x4 c) {
#if __has_builtin(__builtin_amdgcn_mfma_f32_16x16x16bf16_1k)
  return __builtin_amdgcn_mfma_f32_16x16x16bf16_1k(a, b, c, 0, 0, 0);
#else
  asm("v_mfma_f32_16x16x16_bf16 %0, %1, %2, %0" : "+v"(c) : "v"(a), "v"(b));
  return c;
#endif
}

__device__ __forceinline__ void gl_lds16(const void* g, void* l) {
  __builtin_amdgcn_global_load_lds(
      (const __attribute__((address_space(1))) unsigned int*)g,
      (__attribute__((address_space(3))) unsigned int*)l, 16, 0, 0);
}

// ---------------- convert x fp32 -> bf16 ----------------
__global__ __launch_bounds__(256) void cvt_x_k(const float* __restrict__ x,
                                               u16* __restrict__ xb) {
  int i = (blockIdx.x * 256 + threadIdx.x) * 4;
  float4 v = *(const float4*)(x + i);
  u16x4 o = { f2bf(v.x), f2bf(v.y), f2bf(v.z), f2bf(v.w) };
  *(u16x4*)(xb + i) = o;
}

// ---------------- transpose + convert weight: wt[n][k] = w[k][n], K=768 ----
__global__ __launch_bounds__(256) void cvt_wt_k(const float* __restrict__ w,
                                                u16* __restrict__ wt, int N) {
  int i = blockIdx.x * 256 + threadIdx.x;  // over N*768
  int nn = i / 768, kk = i % 768;
  wt[i] = f2bf(w[(size_t)kk * N + nn]);
}

// ---------------- CPB bias MLP: 729 entries x (2->512->24), 16*sigmoid -----
__device__ __forceinline__ float cpb_coord(int v) {
  float c = (float)(v - 13) * (8.0f / 13.0f);
  float a = fabsf(c);
  float r = log2f(a + 1.0f) * (1.0f / 3.0f);
  return c < 0.f ? -r : r;
}

__global__ __launch_bounds__(64) void bias_mlp_k(
    const float* __restrict__ w1, const float* __restrict__ b1,
    const float* __restrict__ w2, const float* __restrict__ b2,
    float* __restrict__ btab) {
  int e = blockIdx.x;
  int lane = threadIdx.x;
  float t0 = cpb_coord(e / 27), t1 = cpb_coord(e % 27);
  float acc[24];
#pragma unroll
  for (int hh = 0; hh < 24; hh++) acc[hh] = 0.f;
#pragma unroll
  for (int jj = 0; jj < 8; jj++) {
    int j = lane * 8 + jj;
    float h1 = t0 * w1[j] + t1 * w1[512 + j] + b1[j];
    h1 = fmaxf(h1, 0.f);
#pragma unroll
    for (int hh = 0; hh < 24; hh++) acc[hh] += h1 * w2[j * 24 + hh];
  }
#pragma unroll
  for (int hh = 0; hh < 24; hh++)
#pragma unroll
    for (int m = 1; m < 64; m <<= 1) acc[hh] += __shfl_xor(acc[hh], m, 64);
  if (lane == 0) {
#pragma unroll
    for (int hh = 0; hh < 24; hh++) {
      float v = acc[hh] + b2[hh];
      btab[e * 24 + hh] = 16.f / (1.f + __expf(-v));
    }
  }
}

// ---------------- expand bias to [24][196][208] fp32, pre-scaled by log2e --
__global__ __launch_bounds__(256) void bias_expand_k(const float* __restrict__ tab,
                                                     float* __restrict__ be) {
  int i = blockIdx.x * 256 + threadIdx.x;  // 24*196*208
  int h = i / (196 * 208);
  int rem = i % (196 * 208);
  int row = rem / 208, col = rem % 208;
  float v = 0.f;
  if (col < 196) {
    int dy = row / 14 - col / 14 + 13;
    int dx = row % 14 - col % 14 + 13;
    v = tab[(dy * 27 + dx) * 24 + h] * 1.4426950408889634f;
  }
  be[i] = v;
}

// ---------------- GEMM: C = A[M][K] * Bt[N][K]^T + bias -------------------
// Natural row-major output. EPI=0: bf16 to Cb. EPI=1: fp32 to Cf.
// BK=64, chunk-XOR LDS swizzle, XCD-chunked block swizzle (nwg % 8 == 0).
template <int EPI>
__global__ __launch_bounds__(256) void gemm_k(
    const u16* __restrict__ A, const u16* __restrict__ Bt,
    const float* __restrict__ bias, float* __restrict__ Cf,
    u16* __restrict__ Cb, int N, int K, int nbx) {
  __shared__ u16 As[128 * 64];
  __shared__ u16 Bs[128 * 64];
  const int tid = threadIdx.x, lane = tid & 63, w = tid >> 6;
  const int r16 = lane & 15, q4 = lane >> 4;
  const int wr = w >> 1, wc = w & 1;
  // XCD-chunked bijective swizzle: same-m blocks grouped per XCD
  const int nwg = gridDim.x, cpx = nwg >> 3;
  const int swz = (blockIdx.x & 7) * cpx + (blockIdx.x >> 3);
  const int m0 = (swz / nbx) * 128, n0 = (swz % nbx) * 128;

  f32x4 acc[4][4] = {};

  for (int k0 = 0; k0 < K; k0 += 64) {
#pragma unroll
    for (int g = 0; g < 4; g++) {
      int chunk = (w * 4 + g) * 64 + lane;
      int row = chunk >> 3, p = chunk & 7;
      int gch = p ^ (row & 7);
      gl_lds16(A + (size_t)(m0 + row) * K + k0 + gch * 8, (char*)As + (w * 4 + g) * 1024);
      gl_lds16(Bt + (size_t)(n0 + row) * K + k0 + gch * 8, (char*)Bs + (w * 4 + g) * 1024);
    }
    __syncthreads();
#pragma unroll
    for (int kk = 0; kk < 2; kk++) {
      short8 af[4], bfr[4];
#pragma unroll
      for (int i = 0; i < 4; i++) {
        int row = wr * 64 + i * 16 + r16;
        int pc = (kk * 4 + q4) ^ (r16 & 7);
        af[i] = *(const short8*)((const char*)As + row * 128 + pc * 16);
      }
#pragma unroll
      for (int j = 0; j < 4; j++) {
        int row = wc * 64 + j * 16 + r16;
        int pc = (kk * 4 + q4) ^ (r16 & 7);
        bfr[j] = *(const short8*)((const char*)Bs + row * 128 + pc * 16);
      }
#pragma unroll
      for (int i = 0; i < 4; i++)
#pragma unroll
        for (int j = 0; j < 4; j++) acc[i][j] = mfma16(af[i], bfr[j], acc[i][j]);
    }
    __syncthreads();
  }

  // epilogue: natural row-major writes, no div/mod
  const int nb = n0 + wc * 64 + r16;
  float bn[4];
#pragma unroll
  for (int j = 0; j < 4; j++) bn[j] = bias[nb + j * 16];
#pragma unroll
  for (int i = 0; i < 4; i++) {
#pragma unroll
    for (int r = 0; r < 4; r++) {
      int m = m0 + wr * 64 + i * 16 + q4 * 4 + r;
      if (EPI == 1) {
        float* cp = Cf + (size_t)m * N + nb;
#pragma unroll
        for (int j = 0; j < 4; j++) cp[j * 16] = acc[i][j][r] + bn[j];
      } else {
        u16* cp = Cb + (size_t)m * N + nb;
#pragma unroll
        for (int j = 0; j < 4; j++) cp[j * 16] = f2bf(acc[i][j][r] + bn[j]);
      }
    }
  }
}

// ---------------- attention: one block per (b,h) --------------------------
// Swapped QK^T (S^T = mfma(K,Q)) -> P is lane-local -> PV via 16x16x16 MFMA.
// q/k/v live in qkv[25088][2304]: q at col h*32, k at 768+h*32, v at 1536+h*32
__global__ __launch_bounds__(256, 4) void attn_k(
    const u16* __restrict__ qkv, const float* __restrict__ be,
    u16* __restrict__ ao) {
  constexpr int VST = 236;
  __shared__ u16 Ks[208 * 32];   // swizzled 16B chunks, rows 0..207
  __shared__ u16 Vt[32 * VST];   // V transposed: Vt[d][n]
  const int tid = threadIdx.x, lane = tid & 63, w = tid >> 6;
  const int r16 = lane & 15, q4 = lane >> 4;
  const int bh = blockIdx.x, b = bh / 24, h = bh % 24;
  const u16* qp = qkv + (size_t)(b * 196) * 2304 + h * 32;
  const u16* kp = qp + 768;
  const u16* vp = qp + 1536;
  const float* bp = be + h * (196 * 208);
  const int ksw = (q4 ^ ((r16 >> 1) & 3)) * 16;
  const float SC2 = 0.17677669529663687f * 1.4426950408889634f;  // 1/sqrt(32)*log2e

  // stage K rows 0..207 (rows >=196 are finite garbage; masked in softmax)
  for (int g = w; g < 13; g += 4) {
    int chunk = g * 64 + lane;
    int row = chunk >> 2;
    int gch = (chunk & 3) ^ ((row >> 1) & 3);
    gl_lds16(kp + (size_t)row * 2304 + gch * 8, (char*)Ks + g * 1024);
  }
  // stage V transposed (rows 0..195 only)
  for (int c = tid; c < 784; c += 256) {
    int n = c >> 2, d0 = (c & 3) * 8;
    u16x8 vv = *(const u16x8*)(vp + (size_t)n * 2304 + (c & 3) * 8);
#pragma unroll
    for (int jj = 0; jj < 8; jj++) Vt[(d0 + jj) * VST + n] = vv[jj];
  }
  // zero Vt pad cols 196..235 (avoid NaN bits; P=0 there anyway)
  for (int idx = tid; idx < 32 * 40; idx += 256) {
    int d = idx / 40, n = 196 + idx % 40;
    Vt[d * VST + n] = 0;
  }
  __syncthreads();

  const f32x4 z = {0.f, 0.f, 0.f, 0.f};
  for (int si = w; si < 13; si += 4) {
    // Q fragment as B operand: lane holds Q[row si*16+r16][d = q4*8..+7]
    short8 bq = *(const short8*)(qp + (size_t)(si * 16 + r16) * 2304 + q4 * 8);
    // S^T tiles: lane (r16,q4) reg r holds S[q=r16][k=16t+q4*4+r]
    f32x4 p[13];
#pragma unroll
    for (int t = 0; t < 13; t++) {
      short8 ka = *(const short8*)((const char*)Ks + (t * 16 + r16) * 64 + ksw);
      p[t] = mfma16(ka, bq, z);
    }
    // bias (pre-scaled by log2e) + scale + mask + in-lane max
    int gc = si * 16 + r16;
    gc = gc < 196 ? gc : 195;
    const float* brow = bp + gc * 208 + q4 * 4;
    float mx = -3e38f;
#pragma unroll
    for (int t = 0; t < 13; t++) {
      float4 bv = *(const float4*)(brow + t * 16);
      int k0 = t * 16 + q4 * 4;
      p[t][0] = (k0 + 0 < 196) ? p[t][0] * SC2 + bv.x : -3e38f;
      p[t][1] = (k0 + 1 < 196) ? p[t][1] * SC2 + bv.y : -3e38f;
      p[t][2] = (k0 + 2 < 196) ? p[t][2] * SC2 + bv.z : -3e38f;
      p[t][3] = (k0 + 3 < 196) ? p[t][3] * SC2 + bv.w : -3e38f;
      mx = fmaxf(mx, fmaxf(fmaxf(p[t][0], p[t][1]), fmaxf(p[t][2], p[t][3])));
    }
    // cross-group reduce (lanes r16, r16+16, r16+32, r16+48 share q-row)
    mx = fmaxf(mx, __shfl_xor(mx, 16, 64));
    mx = fmaxf(mx, __shfl_xor(mx, 32, 64));
    float sum = 0.f;
#pragma unroll
    for (int t = 0; t < 13; t++)
#pragma unroll
      for (int r = 0; r < 4; r++) {
        float e = __builtin_amdgcn_exp2f(p[t][r] - mx);
        p[t][r] = e;
        sum += e;
      }
    sum += __shfl_xor(sum, 16, 64);
    sum += __shfl_xor(sum, 32, 64);
    float rs = 1.0f / sum;
    // PV: P stays in registers as 16x16x16 A-frags; V^T frag = ds_read_b64
    f32x4 o0 = z, o1 = z;
#pragma unroll
    for (int t = 0; t < 13; t++) {
      short4v pa;
#pragma unroll
      for (int r = 0; r < 4; r++) pa[r] = (short)f2bf(p[t][r] * rs);
      const u16* vrow = &Vt[r16 * VST + t * 16 + q4 * 4];
      short4v b0 = *(const short4v*)vrow;
      short4v b1 = *(const short4v*)(vrow + 16 * VST);
      o0 = mfma16x16(pa, b0, o0);
      o1 = mfma16x16(pa, b1, o1);
    }
    // write O (bf16): lane (r16,q4) reg r -> row q4*4+r, col d=r16 (+16)
#pragma unroll
    for (int r = 0; r < 4; r++) {
      int grow = si * 16 + q4 * 4 + r;
      if (grow < 196) {
        u16* op = ao + ((size_t)(b * 196 + grow)) * 768 + h * 32;
        op[r16] = f2bf(o0[r]);
        op[16 + r16] = f2bf(o1[r]);
      }
    }
  }
}

// ---------------------------------------------------------------------------
extern "C" void kernel_launch(void* const* d_in, const int* in_sizes, int n_in,
                              void* d_out, int out_size, void* d_ws, size_t ws_size,
                              hipStream_t stream) {
  const float* x = (const float*)d_in[0];
  const float* qkv_w = (const float*)d_in[1];
  const float* qkv_b = (const float*)d_in[2];
  const float* proj_w = (const float*)d_in[3];
  const float* proj_b = (const float*)d_in[4];
  const float* cpb_w1 = (const float*)d_in[5];
  const float* cpb_b1 = (const float*)d_in[6];
  const float* cpb_w2 = (const float*)d_in[7];
  const float* cpb_b2 = (const float*)d_in[8];
  float* out = (float*)d_out;

  char* ws = (char*)d_ws;
  size_t o = 0;
  auto alloc = [&](size_t sz) {
    size_t r = o;
    o = (o + sz + 255) & ~(size_t)255;
    return r;
  };
  const size_t ME = (size_t)25088 * 768;  // elems per [B,N,DIM]-sized tensor
  u16* x_bf = (u16*)(ws + alloc(ME * 2));           // also aliased as attnout
  u16* wq_t = (u16*)(ws + alloc((size_t)2304 * 768 * 2));
  u16* wp_t = (u16*)(ws + alloc((size_t)768 * 768 * 2));
  u16* qkv_s = (u16*)(ws + alloc(3 * ME * 2));      // [25088][2304] bf16
  float* btab = (float*)(ws + alloc((size_t)729 * 24 * 4));   // also OOB-read pad
  float* bexp = (float*)(ws + alloc((size_t)24 * 196 * 208 * 4));
  u16* ao = x_bf;  // alias: x_bf dead after qkv GEMM

  cvt_x_k<<<18816, 256, 0, stream>>>(x, x_bf);
  cvt_wt_k<<<6912, 256, 0, stream>>>(qkv_w, wq_t, 2304);
  cvt_wt_k<<<2304, 256, 0, stream>>>(proj_w, wp_t, 768);
  bias_mlp_k<<<729, 64, 0, stream>>>(cpb_w1, cpb_b1, cpb_w2, cpb_b2, btab);
  bias_expand_k<<<3822, 256, 0, stream>>>(btab, bexp);
  gemm_k<0><<<3528, 256, 0, stream>>>(x_bf, wq_t, qkv_b, nullptr, qkv_s,
                                      2304, 768, 18);
  attn_k<<<3072, 256, 0, stream>>>(qkv_s, bexp, ao);
  gemm_k<1><<<1176, 256, 0, stream>>>(ao, wp_t, proj_b, out, nullptr,
                                      768, 768, 6);
}

// Round 4
// 347.242 us; speedup vs baseline: 1.3087x; 1.3087x over previous
//
#include <hip/hip_runtime.h>
#include <hip/hip_bf16.h>

typedef unsigned short u16;
typedef __attribute__((ext_vector_type(8))) short short8;
typedef __attribute__((ext_vector_type(4))) short short4v;
typedef __attribute__((ext_vector_type(8))) u16 u16x8;
typedef __attribute__((ext_vector_type(4))) u16 u16x4;
typedef __attribute__((ext_vector_type(4))) float f32x4;

__device__ __forceinline__ u16 f2bf(float f) {
  __hip_bfloat16 h = __float2bfloat16(f);
  u16 u;
  __builtin_memcpy(&u, &h, 2);
  return u;
}

__device__ __forceinline__ f32x4 mfma16(short8 a, short8 b, f32x4 c) {
  return __builtin_amdgcn_mfma_f32_16x16x32_bf16(a, b, c, 0, 0, 0);
}

__device__ __forceinline__ f32x4 mfma16x16(short4v a, short4v b, f32x4 c) {
#if __has_builtin(__builtin_amdgcn_mfma_f32_16x16x16bf16_1k)
  return __builtin_amdgcn_mfma_f32_16x16x16bf16_1k(a, b, c, 0, 0, 0);
#else
  asm("v_mfma_f32_16x16x16_bf16 %0, %1, %2, %0" : "+v"(c) : "v"(a), "v"(b));
  return c;
#endif
}

__device__ __forceinline__ void gl_lds16(const void* g, void* l) {
  __builtin_amdgcn_global_load_lds(
      (const __attribute__((address_space(1))) unsigned int*)g,
      (__attribute__((address_space(3))) unsigned int*)l, 16, 0, 0);
}

// ---------------- convert x fp32 -> bf16 ----------------
__global__ __launch_bounds__(256) void cvt_x_k(const float* __restrict__ x,
                                               u16* __restrict__ xb) {
  int i = (blockIdx.x * 256 + threadIdx.x) * 4;
  float4 v = *(const float4*)(x + i);
  u16x4 o = { f2bf(v.x), f2bf(v.y), f2bf(v.z), f2bf(v.w) };
  *(u16x4*)(xb + i) = o;
}

// ---------------- transpose + convert weight: wt[n][k] = w[k][n], K=768 ----
__global__ __launch_bounds__(256) void cvt_wt_k(const float* __restrict__ w,
                                                u16* __restrict__ wt, int N) {
  int i = blockIdx.x * 256 + threadIdx.x;  // over N*768
  int nn = i / 768, kk = i % 768;
  wt[i] = f2bf(w[(size_t)kk * N + nn]);
}

// ---------------- CPB bias MLP: 729 entries x (2->512->24), 16*sigmoid -----
__device__ __forceinline__ float cpb_coord(int v) {
  float c = (float)(v - 13) * (8.0f / 13.0f);
  float a = fabsf(c);
  float r = log2f(a + 1.0f) * (1.0f / 3.0f);
  return c < 0.f ? -r : r;
}

__global__ __launch_bounds__(64) void bias_mlp_k(
    const float* __restrict__ w1, const float* __restrict__ b1,
    const float* __restrict__ w2, const float* __restrict__ b2,
    float* __restrict__ btab) {
  int e = blockIdx.x;
  int lane = threadIdx.x;
  float t0 = cpb_coord(e / 27), t1 = cpb_coord(e % 27);
  float acc[24];
#pragma unroll
  for (int hh = 0; hh < 24; hh++) acc[hh] = 0.f;
#pragma unroll
  for (int jj = 0; jj < 8; jj++) {
    int j = lane * 8 + jj;
    float h1 = t0 * w1[j] + t1 * w1[512 + j] + b1[j];
    h1 = fmaxf(h1, 0.f);
#pragma unroll
    for (int hh = 0; hh < 24; hh++) acc[hh] += h1 * w2[j * 24 + hh];
  }
#pragma unroll
  for (int hh = 0; hh < 24; hh++)
#pragma unroll
    for (int m = 1; m < 64; m <<= 1) acc[hh] += __shfl_xor(acc[hh], m, 64);
  if (lane == 0) {
#pragma unroll
    for (int hh = 0; hh < 24; hh++) {
      float v = acc[hh] + b2[hh];
      btab[e * 24 + hh] = 16.f / (1.f + __expf(-v));
    }
  }
}

// ---------------- expand bias to [24][196][208] fp32, pre-scaled by log2e --
__global__ __launch_bounds__(256) void bias_expand_k(const float* __restrict__ tab,
                                                     float* __restrict__ be) {
  int i = blockIdx.x * 256 + threadIdx.x;  // 24*196*208
  int h = i / (196 * 208);
  int rem = i % (196 * 208);
  int row = rem / 208, col = rem % 208;
  float v = 0.f;
  if (col < 196) {
    int dy = row / 14 - col / 14 + 13;
    int dx = row % 14 - col % 14 + 13;
    v = tab[(dy * 27 + dx) * 24 + h] * 1.4426950408889634f;
  }
  be[i] = v;
}

// ---------------- GEMM: C = A[M][K] * Bt[N][K]^T + bias -------------------
// Natural row-major output. EPI=0: bf16 to Cb. EPI=1: fp32 to Cf.
// BK=64, chunk-XOR LDS swizzle, XCD-chunked block swizzle (nwg % 8 == 0).
template <int EPI>
__global__ __launch_bounds__(256) void gemm_k(
    const u16* __restrict__ A, const u16* __restrict__ Bt,
    const float* __restrict__ bias, float* __restrict__ Cf,
    u16* __restrict__ Cb, int N, int K, int nbx) {
  __shared__ u16 As[128 * 64];
  __shared__ u16 Bs[128 * 64];
  const int tid = threadIdx.x, lane = tid & 63, w = tid >> 6;
  const int r16 = lane & 15, q4 = lane >> 4;
  const int wr = w >> 1, wc = w & 1;
  // XCD-chunked bijective swizzle: same-m blocks grouped per XCD
  const int nwg = gridDim.x, cpx = nwg >> 3;
  const int swz = (blockIdx.x & 7) * cpx + (blockIdx.x >> 3);
  const int m0 = (swz / nbx) * 128, n0 = (swz % nbx) * 128;

  f32x4 acc[4][4] = {};

  for (int k0 = 0; k0 < K; k0 += 64) {
#pragma unroll
    for (int g = 0; g < 4; g++) {
      int chunk = (w * 4 + g) * 64 + lane;
      int row = chunk >> 3, p = chunk & 7;
      int gch = p ^ (row & 7);
      gl_lds16(A + (size_t)(m0 + row) * K + k0 + gch * 8, (char*)As + (w * 4 + g) * 1024);
      gl_lds16(Bt + (size_t)(n0 + row) * K + k0 + gch * 8, (char*)Bs + (w * 4 + g) * 1024);
    }
    __syncthreads();
#pragma unroll
    for (int kk = 0; kk < 2; kk++) {
      short8 af[4], bfr[4];
#pragma unroll
      for (int i = 0; i < 4; i++) {
        int row = wr * 64 + i * 16 + r16;
        int pc = (kk * 4 + q4) ^ (r16 & 7);
        af[i] = *(const short8*)((const char*)As + row * 128 + pc * 16);
      }
#pragma unroll
      for (int j = 0; j < 4; j++) {
        int row = wc * 64 + j * 16 + r16;
        int pc = (kk * 4 + q4) ^ (r16 & 7);
        bfr[j] = *(const short8*)((const char*)Bs + row * 128 + pc * 16);
      }
#pragma unroll
      for (int i = 0; i < 4; i++)
#pragma unroll
        for (int j = 0; j < 4; j++) acc[i][j] = mfma16(af[i], bfr[j], acc[i][j]);
    }
    __syncthreads();
  }

  // epilogue: natural row-major writes, no div/mod
  const int nb = n0 + wc * 64 + r16;
  float bn[4];
#pragma unroll
  for (int j = 0; j < 4; j++) bn[j] = bias[nb + j * 16];
#pragma unroll
  for (int i = 0; i < 4; i++) {
#pragma unroll
    for (int r = 0; r < 4; r++) {
      int m = m0 + wr * 64 + i * 16 + q4 * 4 + r;
      if (EPI == 1) {
        float* cp = Cf + (size_t)m * N + nb;
#pragma unroll
        for (int j = 0; j < 4; j++) cp[j * 16] = acc[i][j][r] + bn[j];
      } else {
        u16* cp = Cb + (size_t)m * N + nb;
#pragma unroll
        for (int j = 0; j < 4; j++) cp[j * 16] = f2bf(acc[i][j][r] + bn[j]);
      }
    }
  }
}

// ---------------- attention: one block per (b,h) --------------------------
// Swapped QK^T (S^T = mfma(K,Q)) -> P is lane-local -> PV via 16x16x16 MFMA.
// NOTE: no min-waves hint — (256,4) forced VGPR=64 and spilled p[13] to
// scratch (WRITE_SIZE 37->342MB, 2.2x slower). Let the allocator run free.
__global__ __launch_bounds__(256) void attn_k(
    const u16* __restrict__ qkv, const float* __restrict__ be,
    u16* __restrict__ ao) {
  constexpr int VST = 236;
  __shared__ u16 Ks[208 * 32];   // swizzled 16B chunks, rows 0..207
  __shared__ u16 Vt[32 * VST];   // V transposed: Vt[d][n]
  const int tid = threadIdx.x, lane = tid & 63, w = tid >> 6;
  const int r16 = lane & 15, q4 = lane >> 4;
  const int bh = blockIdx.x, b = bh / 24, h = bh % 24;
  const u16* qp = qkv + (size_t)(b * 196) * 2304 + h * 32;
  const u16* kp = qp + 768;
  const u16* vp = qp + 1536;
  const float* bp = be + h * (196 * 208);
  const int ksw = (q4 ^ ((r16 >> 1) & 3)) * 16;
  const float SC2 = 0.17677669529663687f * 1.4426950408889634f;  // 1/sqrt(32)*log2e

  // stage K rows 0..207 (rows >=196 are finite garbage; masked in softmax)
  for (int g = w; g < 13; g += 4) {
    int chunk = g * 64 + lane;
    int row = chunk >> 2;
    int gch = (chunk & 3) ^ ((row >> 1) & 3);
    gl_lds16(kp + (size_t)row * 2304 + gch * 8, (char*)Ks + g * 1024);
  }
  // stage V transposed (rows 0..195 only)
  for (int c = tid; c < 784; c += 256) {
    int n = c >> 2, d0 = (c & 3) * 8;
    u16x8 vv = *(const u16x8*)(vp + (size_t)n * 2304 + (c & 3) * 8);
#pragma unroll
    for (int jj = 0; jj < 8; jj++) Vt[(d0 + jj) * VST + n] = vv[jj];
  }
  // zero Vt pad cols 196..235 (avoid NaN bits; P=0 there anyway)
  for (int idx = tid; idx < 32 * 40; idx += 256) {
    int d = idx / 40, n = 196 + idx % 40;
    Vt[d * VST + n] = 0;
  }
  __syncthreads();

  const f32x4 z = {0.f, 0.f, 0.f, 0.f};
  for (int si = w; si < 13; si += 4) {
    // Q fragment as B operand: lane holds Q[row si*16+r16][d = q4*8..+7]
    short8 bq = *(const short8*)(qp + (size_t)(si * 16 + r16) * 2304 + q4 * 8);
    // S^T tiles: lane (r16,q4) reg r holds S[q=r16][k=16t+q4*4+r]
    f32x4 p[13];
#pragma unroll
    for (int t = 0; t < 13; t++) {
      short8 ka = *(const short8*)((const char*)Ks + (t * 16 + r16) * 64 + ksw);
      p[t] = mfma16(ka, bq, z);
    }
    // bias (pre-scaled by log2e) + scale + mask + in-lane max
    int gc = si * 16 + r16;
    gc = gc < 196 ? gc : 195;
    const float* brow = bp + gc * 208 + q4 * 4;
    float mx = -3e38f;
#pragma unroll
    for (int t = 0; t < 13; t++) {
      float4 bv = *(const float4*)(brow + t * 16);
      int k0 = t * 16 + q4 * 4;
      p[t][0] = (k0 + 0 < 196) ? p[t][0] * SC2 + bv.x : -3e38f;
      p[t][1] = (k0 + 1 < 196) ? p[t][1] * SC2 + bv.y : -3e38f;
      p[t][2] = (k0 + 2 < 196) ? p[t][2] * SC2 + bv.z : -3e38f;
      p[t][3] = (k0 + 3 < 196) ? p[t][3] * SC2 + bv.w : -3e38f;
      mx = fmaxf(mx, fmaxf(fmaxf(p[t][0], p[t][1]), fmaxf(p[t][2], p[t][3])));
    }
    // cross-group reduce (lanes r16, r16+16, r16+32, r16+48 share q-row)
    mx = fmaxf(mx, __shfl_xor(mx, 16, 64));
    mx = fmaxf(mx, __shfl_xor(mx, 32, 64));
    float sum = 0.f;
#pragma unroll
    for (int t = 0; t < 13; t++)
#pragma unroll
      for (int r = 0; r < 4; r++) {
        float e = __builtin_amdgcn_exp2f(p[t][r] - mx);
        p[t][r] = e;
        sum += e;
      }
    sum += __shfl_xor(sum, 16, 64);
    sum += __shfl_xor(sum, 32, 64);
    float rs = 1.0f / sum;
    // PV: P stays in registers as 16x16x16 A-frags; V^T frag = ds_read_b64
    f32x4 o0 = z, o1 = z;
#pragma unroll
    for (int t = 0; t < 13; t++) {
      short4v pa;
#pragma unroll
      for (int r = 0; r < 4; r++) pa[r] = (short)f2bf(p[t][r] * rs);
      const u16* vrow = &Vt[r16 * VST + t * 16 + q4 * 4];
      short4v b0 = *(const short4v*)vrow;
      short4v b1 = *(const short4v*)(vrow + 16 * VST);
      o0 = mfma16x16(pa, b0, o0);
      o1 = mfma16x16(pa, b1, o1);
    }
    // write O (bf16): lane (r16,q4) reg r -> row q4*4+r, col d=r16 (+16)
#pragma unroll
    for (int r = 0; r < 4; r++) {
      int grow = si * 16 + q4 * 4 + r;
      if (grow < 196) {
        u16* op = ao + ((size_t)(b * 196 + grow)) * 768 + h * 32;
        op[r16] = f2bf(o0[r]);
        op[16 + r16] = f2bf(o1[r]);
      }
    }
  }
}

// ---------------------------------------------------------------------------
extern "C" void kernel_launch(void* const* d_in, const int* in_sizes, int n_in,
                              void* d_out, int out_size, void* d_ws, size_t ws_size,
                              hipStream_t stream) {
  const float* x = (const float*)d_in[0];
  const float* qkv_w = (const float*)d_in[1];
  const float* qkv_b = (const float*)d_in[2];
  const float* proj_w = (const float*)d_in[3];
  const float* proj_b = (const float*)d_in[4];
  const float* cpb_w1 = (const float*)d_in[5];
  const float* cpb_b1 = (const float*)d_in[6];
  const float* cpb_w2 = (const float*)d_in[7];
  const float* cpb_b2 = (const float*)d_in[8];
  float* out = (float*)d_out;

  char* ws = (char*)d_ws;
  size_t o = 0;
  auto alloc = [&](size_t sz) {
    size_t r = o;
    o = (o + sz + 255) & ~(size_t)255;
    return r;
  };
  const size_t ME = (size_t)25088 * 768;  // elems per [B,N,DIM]-sized tensor
  u16* x_bf = (u16*)(ws + alloc(ME * 2));           // also aliased as attnout
  u16* wq_t = (u16*)(ws + alloc((size_t)2304 * 768 * 2));
  u16* wp_t = (u16*)(ws + alloc((size_t)768 * 768 * 2));
  u16* qkv_s = (u16*)(ws + alloc(3 * ME * 2));      // [25088][2304] bf16
  float* btab = (float*)(ws + alloc((size_t)729 * 24 * 4));   // also OOB-read pad
  float* bexp = (float*)(ws + alloc((size_t)24 * 196 * 208 * 4));
  u16* ao = x_bf;  // alias: x_bf dead after qkv GEMM

  cvt_x_k<<<18816, 256, 0, stream>>>(x, x_bf);
  cvt_wt_k<<<6912, 256, 0, stream>>>(qkv_w, wq_t, 2304);
  cvt_wt_k<<<2304, 256, 0, stream>>>(proj_w, wp_t, 768);
  bias_mlp_k<<<729, 64, 0, stream>>>(cpb_w1, cpb_b1, cpb_w2, cpb_b2, btab);
  bias_expand_k<<<3822, 256, 0, stream>>>(btab, bexp);
  gemm_k<0><<<3528, 256, 0, stream>>>(x_bf, wq_t, qkv_b, nullptr, qkv_s,
                                      2304, 768, 18);
  attn_k<<<3072, 256, 0, stream>>>(qkv_s, bexp, ao);
  gemm_k<1><<<1176, 256, 0, stream>>>(ao, wp_t, proj_b, out, nullptr,
                                      768, 768, 6);
}

// Round 6
// 287.918 us; speedup vs baseline: 1.5783x; 1.2060x over previous
//
#include <hip/hip_runtime.h>
#include <hip/hip_bf16.h>

typedef unsigned short u16;
typedef __attribute__((ext_vector_type(8))) short short8;
typedef __attribute__((ext_vector_type(4))) short short4v;
typedef __attribute__((ext_vector_type(8))) u16 u16x8;
typedef __attribute__((ext_vector_type(4))) u16 u16x4;
typedef __attribute__((ext_vector_type(4))) float f32x4;

__device__ __forceinline__ u16 f2bf(float f) {
  __hip_bfloat16 h = __float2bfloat16(f);
  u16 u;
  __builtin_memcpy(&u, &h, 2);
  return u;
}

__device__ __forceinline__ f32x4 mfma16(short8 a, short8 b, f32x4 c) {
  return __builtin_amdgcn_mfma_f32_16x16x32_bf16(a, b, c, 0, 0, 0);
}

__device__ __forceinline__ f32x4 mfma16x16(short4v a, short4v b, f32x4 c) {
#if __has_builtin(__builtin_amdgcn_mfma_f32_16x16x16bf16_1k)
  return __builtin_amdgcn_mfma_f32_16x16x16bf16_1k(a, b, c, 0, 0, 0);
#else
  asm("v_mfma_f32_16x16x16_bf16 %0, %1, %2, %0" : "+v"(c) : "v"(a), "v"(b));
  return c;
#endif
}

__device__ __forceinline__ void gl_lds16(const void* g, void* l) {
  __builtin_amdgcn_global_load_lds(
      (const __attribute__((address_space(1))) unsigned int*)g,
      (__attribute__((address_space(3))) unsigned int*)l, 16, 0, 0);
}

// ---------------- convert x fp32 -> bf16 ----------------
__global__ __launch_bounds__(256) void cvt_x_k(const float* __restrict__ x,
                                               u16* __restrict__ xb) {
  int i = (blockIdx.x * 256 + threadIdx.x) * 4;
  float4 v = *(const float4*)(x + i);
  u16x4 o = { f2bf(v.x), f2bf(v.y), f2bf(v.z), f2bf(v.w) };
  *(u16x4*)(xb + i) = o;
}

// ---------------- transpose + convert weight: wt[n][k] = w[k][n], K=768 ----
__global__ __launch_bounds__(256) void cvt_wt_k(const float* __restrict__ w,
                                                u16* __restrict__ wt, int N) {
  int i = blockIdx.x * 256 + threadIdx.x;  // over N*768
  int nn = i / 768, kk = i % 768;
  wt[i] = f2bf(w[(size_t)kk * N + nn]);
}

// ---------------- CPB bias MLP: 729 entries x (2->512->24), 16*sigmoid -----
__device__ __forceinline__ float cpb_coord(int v) {
  float c = (float)(v - 13) * (8.0f / 13.0f);
  float a = fabsf(c);
  float r = log2f(a + 1.0f) * (1.0f / 3.0f);
  return c < 0.f ? -r : r;
}

__global__ __launch_bounds__(64) void bias_mlp_k(
    const float* __restrict__ w1, const float* __restrict__ b1,
    const float* __restrict__ w2, const float* __restrict__ b2,
    float* __restrict__ btab) {
  int e = blockIdx.x;
  int lane = threadIdx.x;
  float t0 = cpb_coord(e / 27), t1 = cpb_coord(e % 27);
  float acc[24];
#pragma unroll
  for (int hh = 0; hh < 24; hh++) acc[hh] = 0.f;
#pragma unroll
  for (int jj = 0; jj < 8; jj++) {
    int j = lane * 8 + jj;
    float h1 = t0 * w1[j] + t1 * w1[512 + j] + b1[j];
    h1 = fmaxf(h1, 0.f);
#pragma unroll
    for (int hh = 0; hh < 24; hh++) acc[hh] += h1 * w2[j * 24 + hh];
  }
#pragma unroll
  for (int hh = 0; hh < 24; hh++)
#pragma unroll
    for (int m = 1; m < 64; m <<= 1) acc[hh] += __shfl_xor(acc[hh], m, 64);
  if (lane == 0) {
#pragma unroll
    for (int hh = 0; hh < 24; hh++) {
      float v = acc[hh] + b2[hh];
      btab[e * 24 + hh] = 16.f / (1.f + __expf(-v));
    }
  }
}

// ---------------- expand bias to [24][196][208] fp32, pre-scaled by log2e --
__global__ __launch_bounds__(256) void bias_expand_k(const float* __restrict__ tab,
                                                     float* __restrict__ be) {
  int i = blockIdx.x * 256 + threadIdx.x;  // 24*196*208
  int h = i / (196 * 208);
  int rem = i % (196 * 208);
  int row = rem / 208, col = rem % 208;
  float v = 0.f;
  if (col < 196) {
    int dy = row / 14 - col / 14 + 13;
    int dx = row % 14 - col % 14 + 13;
    v = tab[(dy * 27 + dx) * 24 + h] * 1.4426950408889634f;
  }
  be[i] = v;
}

// ---------------- GEMM: C = A[M][K] * Bt[N][K]^T + bias -------------------
// Natural row-major output. EPI=0: bf16 to Cb. EPI=1: fp32 to Cf.
// BK=64, chunk-XOR LDS swizzle, XCD-chunked block swizzle (nwg % 8 == 0).
template <int EPI>
__global__ __launch_bounds__(256) void gemm_k(
    const u16* __restrict__ A, const u16* __restrict__ Bt,
    const float* __restrict__ bias, float* __restrict__ Cf,
    u16* __restrict__ Cb, int N, int K, int nbx) {
  __shared__ u16 As[128 * 64];
  __shared__ u16 Bs[128 * 64];
  const int tid = threadIdx.x, lane = tid & 63, w = tid >> 6;
  const int r16 = lane & 15, q4 = lane >> 4;
  const int wr = w >> 1, wc = w & 1;
  // XCD-chunked bijective swizzle: same-m blocks grouped per XCD
  const int nwg = gridDim.x, cpx = nwg >> 3;
  const int swz = (blockIdx.x & 7) * cpx + (blockIdx.x >> 3);
  const int m0 = (swz / nbx) * 128, n0 = (swz % nbx) * 128;

  f32x4 acc[4][4] = {};

  for (int k0 = 0; k0 < K; k0 += 64) {
#pragma unroll
    for (int g = 0; g < 4; g++) {
      int chunk = (w * 4 + g) * 64 + lane;
      int row = chunk >> 3, p = chunk & 7;
      int gch = p ^ (row & 7);
      gl_lds16(A + (size_t)(m0 + row) * K + k0 + gch * 8, (char*)As + (w * 4 + g) * 1024);
      gl_lds16(Bt + (size_t)(n0 + row) * K + k0 + gch * 8, (char*)Bs + (w * 4 + g) * 1024);
    }
    __syncthreads();
#pragma unroll
    for (int kk = 0; kk < 2; kk++) {
      short8 af[4], bfr[4];
#pragma unroll
      for (int i = 0; i < 4; i++) {
        int row = wr * 64 + i * 16 + r16;
        int pc = (kk * 4 + q4) ^ (r16 & 7);
        af[i] = *(const short8*)((const char*)As + row * 128 + pc * 16);
      }
#pragma unroll
      for (int j = 0; j < 4; j++) {
        int row = wc * 64 + j * 16 + r16;
        int pc = (kk * 4 + q4) ^ (r16 & 7);
        bfr[j] = *(const short8*)((const char*)Bs + row * 128 + pc * 16);
      }
#pragma unroll
      for (int i = 0; i < 4; i++)
#pragma unroll
        for (int j = 0; j < 4; j++) acc[i][j] = mfma16(af[i], bfr[j], acc[i][j]);
    }
    __syncthreads();
  }

  // epilogue: natural row-major writes, no div/mod
  const int nb = n0 + wc * 64 + r16;
  float bn[4];
#pragma unroll
  for (int j = 0; j < 4; j++) bn[j] = bias[nb + j * 16];
#pragma unroll
  for (int i = 0; i < 4; i++) {
#pragma unroll
    for (int r = 0; r < 4; r++) {
      int m = m0 + wr * 64 + i * 16 + q4 * 4 + r;
      if (EPI == 1) {
        float* cp = Cf + (size_t)m * N + nb;
#pragma unroll
        for (int j = 0; j < 4; j++) cp[j * 16] = acc[i][j][r] + bn[j];
      } else {
        u16* cp = Cb + (size_t)m * N + nb;
#pragma unroll
        for (int j = 0; j < 4; j++) cp[j * 16] = f2bf(acc[i][j][r] + bn[j]);
      }
    }
  }
}

// ---------------- attention: one block per (b,h) --------------------------
// Swapped QK^T (S^T = mfma(K,Q)) -> P lane-local -> PV via 16x16x16 MFMA.
// No-max softmax (exponents bounded: |S*scale*log2e| <~ 10, bias*log2e <= 23,
// exp2 arg <= ~33 -> max e ~ 2^33, safe in fp32/bf16). 1/sum deferred to
// output with a ROW-TRANSPOSING shuffle: before PV, lane (r16,q4) holds
// q-row r16; after PV its output regs are q-row q4*4+r. rsv[r] must come
// from lane with r16' = q4*4+r (R5 bug: used own lane's sum -> wrong row +
// garbage-row inf/NaN leaked into valid rows).
__global__ __launch_bounds__(256) void attn_k(
    const u16* __restrict__ qkv, const float* __restrict__ be,
    u16* __restrict__ ao) {
  constexpr int VST = 236;
  __shared__ u16 Ks[208 * 32];   // swizzled 16B chunks, rows 0..207
  __shared__ u16 Vt[32 * VST];   // V transposed: Vt[d][n]
  const int tid = threadIdx.x, lane = tid & 63, w = tid >> 6;
  const int r16 = lane & 15, q4 = lane >> 4;
  const int bh = blockIdx.x, b = bh / 24, h = bh % 24;
  const u16* qp = qkv + (size_t)(b * 196) * 2304 + h * 32;
  const u16* kp = qp + 768;
  const u16* vp = qp + 1536;
  const float* bp = be + h * (196 * 208);
  const int ksw = (q4 ^ ((r16 >> 1) & 3)) * 16;
  const float SC2 = 0.17677669529663687f * 1.4426950408889634f;  // 1/sqrt(32)*log2e

  // stage K rows 0..207 (rows >=196 are garbage; their S columns/rows are
  // masked to 0 before any use)
  for (int g = w; g < 13; g += 4) {
    int chunk = g * 64 + lane;
    int row = chunk >> 2;
    int gch = (chunk & 3) ^ ((row >> 1) & 3);
    gl_lds16(kp + (size_t)row * 2304 + gch * 8, (char*)Ks + g * 1024);
  }
  // stage V transposed (rows 0..195 only)
  for (int c = tid; c < 784; c += 256) {
    int n = c >> 2, d0 = (c & 3) * 8;
    u16x8 vv = *(const u16x8*)(vp + (size_t)n * 2304 + (c & 3) * 8);
#pragma unroll
    for (int jj = 0; jj < 8; jj++) Vt[(d0 + jj) * VST + n] = vv[jj];
  }
  // zero Vt pad cols 196..235
  for (int idx = tid; idx < 32 * 40; idx += 256) {
    int d = idx / 40, n = 196 + idx % 40;
    Vt[d * VST + n] = 0;
  }
  __syncthreads();

  const f32x4 z = {0.f, 0.f, 0.f, 0.f};
  // prefetched Q fragment for the first strip
  short8 bq = *(const short8*)(qp + (size_t)(w * 16 + r16) * 2304 + q4 * 8);
  for (int si = w; si < 13; si += 4) {
    // prefetch next strip's Q (hides global latency under softmax+PV)
    short8 bq_next = {};
    if (si + 4 < 13)
      bq_next = *(const short8*)(qp + (size_t)((si + 4) * 16 + r16) * 2304 + q4 * 8);
    // S^T tiles: lane (r16,q4) reg r holds S[q=r16][k=16t+q4*4+r]
    f32x4 p[13];
#pragma unroll
    for (int t = 0; t < 13; t++) {
      short8 ka = *(const short8*)((const char*)Ks + (t * 16 + r16) * 64 + ksw);
      p[t] = mfma16(ka, bq, z);
    }
    bq = bq_next;
    // fused: scale+bias -> exp2 -> bf16 (unnormalized), 4 parallel sum chains
    int gc = si * 16 + r16;
    gc = gc < 196 ? gc : 195;
    const float* brow = bp + gc * 208 + q4 * 4;
    float s0 = 0.f, s1 = 0.f, s2 = 0.f, s3 = 0.f;
    short4v pa[13];
#pragma unroll
    for (int t = 0; t < 12; t++) {   // k0+3 <= 191 < 196: no masking needed
      float4 bv = *(const float4*)(brow + t * 16);
      float e0 = __builtin_amdgcn_exp2f(p[t][0] * SC2 + bv.x);
      float e1 = __builtin_amdgcn_exp2f(p[t][1] * SC2 + bv.y);
      float e2 = __builtin_amdgcn_exp2f(p[t][2] * SC2 + bv.z);
      float e3 = __builtin_amdgcn_exp2f(p[t][3] * SC2 + bv.w);
      s0 += e0; s1 += e1; s2 += e2; s3 += e3;
      pa[t][0] = (short)f2bf(e0);
      pa[t][1] = (short)f2bf(e1);
      pa[t][2] = (short)f2bf(e2);
      pa[t][3] = (short)f2bf(e3);
    }
    {  // t = 12: keys 192..207, mask k >= 196
      float4 bv = *(const float4*)(brow + 12 * 16);
      int k0 = 192 + q4 * 4;
      float e0 = (k0 + 0 < 196) ? __builtin_amdgcn_exp2f(p[12][0] * SC2 + bv.x) : 0.f;
      float e1 = (k0 + 1 < 196) ? __builtin_amdgcn_exp2f(p[12][1] * SC2 + bv.y) : 0.f;
      float e2 = (k0 + 2 < 196) ? __builtin_amdgcn_exp2f(p[12][2] * SC2 + bv.z) : 0.f;
      float e3 = (k0 + 3 < 196) ? __builtin_amdgcn_exp2f(p[12][3] * SC2 + bv.w) : 0.f;
      s0 += e0; s1 += e1; s2 += e2; s3 += e3;
      pa[12][0] = (short)f2bf(e0);
      pa[12][1] = (short)f2bf(e1);
      pa[12][2] = (short)f2bf(e2);
      pa[12][3] = (short)f2bf(e3);
    }
    float sum = (s0 + s1) + (s2 + s3);
    sum += __shfl_xor(sum, 16, 64);
    sum += __shfl_xor(sum, 32, 64);   // now: every lane has total for q-row r16
    float rs = 1.0f / sum;
    // PV with unnormalized P; 4 short accumulator chains
    f32x4 o0a = z, o0b = z, o1a = z, o1b = z;
#pragma unroll
    for (int t = 0; t < 13; t++) {
      const u16* vrow = &Vt[r16 * VST + t * 16 + q4 * 4];
      short4v b0 = *(const short4v*)vrow;
      short4v b1 = *(const short4v*)(vrow + 16 * VST);
      if (t & 1) {
        o0b = mfma16x16(pa[t], b0, o0b);
        o1b = mfma16x16(pa[t], b1, o1b);
      } else {
        o0a = mfma16x16(pa[t], b0, o0a);
        o1a = mfma16x16(pa[t], b1, o1a);
      }
    }
    // write O (bf16): lane (r16,q4) reg r -> q-row q4*4+r, col d=r16 (+16).
    // Fetch the normalizer of q-row q4*4+r from lane (lane&~15)|(q4*4+r).
#pragma unroll
    for (int r = 0; r < 4; r++) {
      float rsv = __shfl(rs, q4 * 4 + r, 16);
      int grow = si * 16 + q4 * 4 + r;
      if (grow < 196) {
        u16* op = ao + ((size_t)(b * 196 + grow)) * 768 + h * 32;
        op[r16] = f2bf((o0a[r] + o0b[r]) * rsv);
        op[16 + r16] = f2bf((o1a[r] + o1b[r]) * rsv);
      }
    }
  }
}

// ---------------------------------------------------------------------------
extern "C" void kernel_launch(void* const* d_in, const int* in_sizes, int n_in,
                              void* d_out, int out_size, void* d_ws, size_t ws_size,
                              hipStream_t stream) {
  const float* x = (const float*)d_in[0];
  const float* qkv_w = (const float*)d_in[1];
  const float* qkv_b = (const float*)d_in[2];
  const float* proj_w = (const float*)d_in[3];
  const float* proj_b = (const float*)d_in[4];
  const float* cpb_w1 = (const float*)d_in[5];
  const float* cpb_b1 = (const float*)d_in[6];
  const float* cpb_w2 = (const float*)d_in[7];
  const float* cpb_b2 = (const float*)d_in[8];
  float* out = (float*)d_out;

  char* ws = (char*)d_ws;
  size_t o = 0;
  auto alloc = [&](size_t sz) {
    size_t r = o;
    o = (o + sz + 255) & ~(size_t)255;
    return r;
  };
  const size_t ME = (size_t)25088 * 768;  // elems per [B,N,DIM]-sized tensor
  u16* x_bf = (u16*)(ws + alloc(ME * 2));           // also aliased as attnout
  u16* wq_t = (u16*)(ws + alloc((size_t)2304 * 768 * 2));
  u16* wp_t = (u16*)(ws + alloc((size_t)768 * 768 * 2));
  u16* qkv_s = (u16*)(ws + alloc(3 * ME * 2));      // [25088][2304] bf16
  float* btab = (float*)(ws + alloc((size_t)729 * 24 * 4));   // also OOB-read pad
  float* bexp = (float*)(ws + alloc((size_t)24 * 196 * 208 * 4));
  u16* ao = x_bf;  // alias: x_bf dead after qkv GEMM

  cvt_x_k<<<18816, 256, 0, stream>>>(x, x_bf);
  cvt_wt_k<<<6912, 256, 0, stream>>>(qkv_w, wq_t, 2304);
  cvt_wt_k<<<2304, 256, 0, stream>>>(proj_w, wp_t, 768);
  bias_mlp_k<<<729, 64, 0, stream>>>(cpb_w1, cpb_b1, cpb_w2, cpb_b2, btab);
  bias_expand_k<<<3822, 256, 0, stream>>>(btab, bexp);
  gemm_k<0><<<3528, 256, 0, stream>>>(x_bf, wq_t, qkv_b, nullptr, qkv_s,
                                      2304, 768, 18);
  attn_k<<<3072, 256, 0, stream>>>(qkv_s, bexp, ao);
  gemm_k<1><<<1176, 256, 0, stream>>>(ao, wp_t, proj_b, out, nullptr,
                                      768, 768, 6);
}